// Round 13
// baseline (176.384 us; speedup 1.0000x reference)
//
#include <hip/hip_runtime.h>
#include <hip/hip_fp16.h>

#define NBLK 256
#define FPAD 16   // 64 B per flag slot

typedef _Float16 h2_t __attribute__((ext_vector_type(2)));

#define AG_LD(p)    __hip_atomic_load((p), __ATOMIC_RELAXED, __HIP_MEMORY_SCOPE_AGENT)
#define AG_ST(p, v) __hip_atomic_store((p), (v), __ATOMIC_RELAXED, __HIP_MEMORY_SCOPE_AGENT)

__device__ __forceinline__ unsigned pkh(float a, float b) {
    const __half2 h = __floats2half2_rn(a, b);
    return __builtin_bit_cast(unsigned, h);
}
__device__ __forceinline__ float fdot2(unsigned w, unsigned a, float c) {
#if __has_builtin(__builtin_amdgcn_fdot2)
    return __builtin_amdgcn_fdot2(__builtin_bit_cast(h2_t, w),
                                  __builtin_bit_cast(h2_t, a), c, false);
#else
    const float2 fw = __half22float2(__builtin_bit_cast(__half2, w));
    const float2 fa = __half22float2(__builtin_bit_cast(__half2, a));
    return c + fw.x * fa.x + fw.y * fa.y;
#endif
}

// Packed fp16 weights: octet g=k>>3; WtH[m*32768 + g*1024 + c*4 + ((k>>1)&3)]
__device__ __forceinline__ uint4 wld(const unsigned* __restrict__ WtH,
                                     int m, int g, int c) {
    return *(const uint4*)(WtH + (size_t)m * 32768 + (size_t)g * 1024 + c * 4);
}

// Global fan-out barrier (validated R5-R12; per-batch variant regressed R11).
__device__ __forceinline__ void gridbar(int n, unsigned* flags, unsigned* rel,
                                        int bid, bool fence) {
    __syncthreads();
    if (threadIdx.x == 0)
        __hip_atomic_store(&flags[bid * FPAD], (unsigned)n, __ATOMIC_RELEASE,
                           __HIP_MEMORY_SCOPE_AGENT);
    if (bid == 0) {
        if (threadIdx.x < NBLK) {
            while ((int)__hip_atomic_load(&flags[threadIdx.x * FPAD],
                                          __ATOMIC_RELAXED,
                                          __HIP_MEMORY_SCOPE_AGENT) < n)
                __builtin_amdgcn_s_sleep(1);
        }
        __syncthreads();
        if (threadIdx.x < 16)
            __hip_atomic_store(&rel[(n * 16 + threadIdx.x) * FPAD], (unsigned)n,
                               __ATOMIC_RELEASE, __HIP_MEMORY_SCOPE_AGENT);
    } else {
        if (threadIdx.x == 0) {
            while ((int)__hip_atomic_load(&rel[(n * 16 + (bid & 15)) * FPAD],
                                          __ATOMIC_RELAXED,
                                          __HIP_MEMORY_SCOPE_AGENT) < n)
                __builtin_amdgcn_s_sleep(1);
        }
    }
    if (fence) __builtin_amdgcn_fence(__ATOMIC_ACQUIRE, "agent");
    __syncthreads();
}

// 4-way phaseB: softmax combine + sigmoid + U2 matvec (k quarter per rq)
// + updB -> accu32[c]. red region reused as scratch. 1024 thr: c, rq=tid>>8.
__device__ __forceinline__ void phaseB4(int i, int b, int c, int rq, int tid,
                                        const float* __restrict__ part,
                                        const unsigned* __restrict__ WtH,
                                        const float* __restrict__ updB,
                                        float* red, float* aggl32,
                                        float* accu32, unsigned* aggh) {
    float M = -1e30f, den = 0.f, num = 0.f;
    const int par = i & 1;
    #pragma unroll
    for (int j = rq * 4; j < rq * 4 + 4; ++j) {
        const float* pp = part + (size_t)(par * 256 + b * 16 + j) * 768;
        const float mj = AG_LD(pp + c);
        const float dj = AG_LD(pp + 256 + c);
        const float nj = AG_LD(pp + 512 + c);
        const float Mn = fmaxf(M, mj);
        const float s = __expf(M - Mn), e = __expf(mj - Mn);
        den = den * s + dj * e;
        num = num * s + nj * e;
        M = Mn;
    }
    red[(rq * 3 + 0) * 256 + c] = M;
    red[(rq * 3 + 1) * 256 + c] = den;
    red[(rq * 3 + 2) * 256 + c] = num;
    __syncthreads();
    if (rq == 0) {
        float Mx = red[c];
        #pragma unroll
        for (int g = 1; g < 4; ++g) Mx = fmaxf(Mx, red[(g * 3) * 256 + c]);
        float dd = 0.f, nn = 0.f;
        #pragma unroll
        for (int g = 0; g < 4; ++g) {
            const float e = __expf(red[(g * 3) * 256 + c] - Mx);
            dd += red[(g * 3 + 1) * 256 + c] * e;
            nn += red[(g * 3 + 2) * 256 + c] * e;
        }
        aggl32[c] = 1.f / (1.f + __expf(-(nn / dd)));
    }
    __syncthreads();
    if (tid < 128) aggh[tid] = pkh(aggl32[2 * tid], aggl32[2 * tid + 1]);
    __syncthreads();
    const int g0 = rq * 8;
    uint4 buf[8];
    #pragma unroll
    for (int j = 0; j < 8; ++j) buf[j] = wld(WtH, 9 + i, g0 + j, c);
    float au = 0.f;
    #pragma unroll
    for (int j = 0; j < 8; ++j) {
        const uint4 w = buf[j];
        const uint4 a = *(const uint4*)&aggh[(g0 + j) * 4];
        au = fdot2(w.x, a.x, au);
        au = fdot2(w.y, a.y, au);
        au = fdot2(w.z, a.z, au);
        au = fdot2(w.w, a.w, au);
    }
    __syncthreads();
    red[rq * 256 + c] = au;
    __syncthreads();
    if (rq == 0)
        accu32[c] = red[c] + red[256 + c] + red[512 + c] + red[768 + c]
                  + updB[i * 256 + c];
    __syncthreads();
}

__global__ __launch_bounds__(1024, 1) void fused_k(
    const float* __restrict__ feat,   // [16][128][256]
    const float* __restrict__ mask,   // [16][128]
    const float* __restrict__ aggW,   // [3][256][256]
    const float* __restrict__ aggB,   // [3][256]
    const float* __restrict__ attnW,  // [3][256][512]
    const float* __restrict__ updW,   // [3][256][512]
    const float* __restrict__ updB,   // [3][256]
    unsigned* __restrict__ WtH,       // 12 * 32768 uints (fp16-pair packed)
    float* __restrict__ part,         // 2 * 256 * 768
    unsigned* flags, unsigned* rel,
    float* __restrict__ out)
{
    __shared__ __align__(16) float ldsf[14984];   // ~58.5 KB -> 1 block/CU
    unsigned* hidh   = (unsigned*)ldsf;           // [0,1024)
    unsigned* xlh    = (unsigned*)ldsf + 1024;    // [1024,2048)
    float*    xl32   = ldsf + 2048;               // [2048,4096)
    float*    xu32   = ldsf + 4096;               // [4096,6144)
    float*    red    = ldsf + 6144;               // [6144,14336) 4x8x256
    float*    aggl32 = ldsf + 14336;              // [14336,14592)
    float*    accu32 = ldsf + 14592;              // [14592,14848)
    unsigned* aggh   = (unsigned*)ldsf + 14848;   // [14848,14976)
    float*    msk    = ldsf + 14976;              // [14976,14984)

    const int bid = blockIdx.x;
    const int tid = threadIdx.x;
    const int c  = tid & 255;
    const int rq = tid >> 8;                  // 0..3, wave-uniform
    const int b  = bid >> 4, jj = bid & 15;
    const int row0 = b * 128 + jj * 8;

    // ---- P0a: stage hid0 = fp16(feat*mask) + mask into LDS (survives fence)
    {
        const int r = tid >> 7, pr = tid & 127;
        const float2 f = *(const float2*)(feat + (size_t)(row0 + r) * 256 + pr * 2);
        const float mv = mask[row0 + r];
        hidh[r * 128 + pr] = pkh(f.x * mv, f.y * mv);
    }
    if (tid < 8) msk[tid] = mask[row0 + tid];

    // ---- P0b: transpose + fp16-pack 12 weight mats (blocks 0..191)
    if (bid < 192) {
        float (*Tl)[65] = (float (*)[65])red;     // overlay
        const int m = bid >> 4, t = bid & 15, tr = t >> 2, tc = t & 3;
        const float* src; int stride, off;
        if (m < 3)      { src = aggW  + (size_t)m * 65536;        stride = 256; off = 0;   }
        else if (m < 6) { src = attnW + (size_t)(m - 3) * 131072; stride = 512; off = 0;   }
        else if (m < 9) { src = updW  + (size_t)(m - 6) * 131072; stride = 512; off = 0;   }
        else            { src = updW  + (size_t)(m - 9) * 131072; stride = 512; off = 256; }
        unsigned* dstu = WtH + (size_t)m * 32768;
        {
            const int row = tid >> 4, q = (tid & 15) * 4;
            const float4 v = *(const float4*)(src + (size_t)(tr * 64 + row) * stride + off + tc * 64 + q);
            Tl[row][q + 0] = v.x; Tl[row][q + 1] = v.y;
            Tl[row][q + 2] = v.z; Tl[row][q + 3] = v.w;
        }
        __syncthreads();
        #pragma unroll
        for (int it = 0; it < 2; ++it) {
            const int j = it * 1024 + tid, cl = j >> 5, pr = j & 31;
            const unsigned val = pkh(Tl[cl][pr * 2], Tl[cl][pr * 2 + 1]);
            const int P = tc * 32 + pr, g = P >> 2, jq = P & 3;
            dstu[(size_t)g * 1024 + (tr * 64 + cl) * 4 + jq] = val;
        }
    }
    gridbar(1, flags, rel, bid, true);   // only fenced barrier

    for (int i = 0; i < 3; ++i) {
        if (i > 0) {
            phaseB4(i - 1, b, c, rq, tid, part, WtH, updB, red, aggl32, accu32, aggh);
            // hid = (xU1 + accU) * mask, packed to fp16
            const int r = tid >> 7, pr = tid & 127;
            const float a0 = xu32[r * 256 + pr * 2]     + accu32[pr * 2];
            const float a1 = xu32[r * 256 + pr * 2 + 1] + accu32[pr * 2 + 1];
            const float mv = msk[r];
            hidh[r * 128 + pr] = pkh(a0 * mv, a1 * mv);
            __syncthreads();
        }

        // ---- P1: x = hid @ aggW^T + aggB. 4-way k-split (1x total stream).
        {
            const int g0 = rq * 8;
            uint4 buf[8];
            #pragma unroll
            for (int j = 0; j < 8; ++j) buf[j] = wld(WtH, i, g0 + j, c);
            float acc[8] = {};
            #pragma unroll
            for (int j = 0; j < 8; ++j) {
                const uint4 w = buf[j];
                const int g = g0 + j;
                #pragma unroll
                for (int r = 0; r < 8; ++r) {
                    const uint4 h = *(const uint4*)&hidh[r * 128 + g * 4];
                    acc[r] = fdot2(w.x, h.x, acc[r]);
                    acc[r] = fdot2(w.y, h.y, acc[r]);
                    acc[r] = fdot2(w.z, h.z, acc[r]);
                    acc[r] = fdot2(w.w, h.w, acc[r]);
                }
            }
            #pragma unroll
            for (int r = 0; r < 8; ++r) red[(rq * 8 + r) * 256 + c] = acc[r];
            __syncthreads();
            // rq finalizes rows 2rq, 2rq+1
            const float bb = aggB[i * 256 + c];
            #pragma unroll
            for (int rr = 0; rr < 2; ++rr) {
                const int r = rq * 2 + rr;
                xl32[r * 256 + c] = red[r * 256 + c] + red[(8 + r) * 256 + c]
                                  + red[(16 + r) * 256 + c] + red[(24 + r) * 256 + c] + bb;
            }
            __syncthreads();
            const int r = tid >> 7, pr = tid & 127;
            xlh[r * 128 + pr] = pkh(xl32[r * 256 + pr * 2], xl32[r * 256 + pr * 2 + 1]);
            __syncthreads();
        }

        // ---- P2: rq0/1 = W1 k-halves -> p ; rq2/3 = U1 k-halves -> xU1
        {
            const int mIdx = (rq < 2 ? 3 : 6) + i;
            const int g0 = (rq & 1) * 16;
            uint4 buf[8];
            #pragma unroll
            for (int j = 0; j < 8; ++j) buf[j] = wld(WtH, mIdx, g0 + j, c);
            float acc[8] = {};
            #pragma unroll
            for (int ph = 0; ph < 2; ++ph) {
                #pragma unroll
                for (int j = 0; j < 8; ++j) {
                    const uint4 w = buf[j];
                    if (ph < 1) buf[j] = wld(WtH, mIdx, g0 + 8 + j, c);
                    const int g = g0 + ph * 8 + j;
                    #pragma unroll
                    for (int r = 0; r < 8; ++r) {
                        const uint4 h = *(const uint4*)&xlh[r * 128 + g * 4];
                        acc[r] = fdot2(w.x, h.x, acc[r]);
                        acc[r] = fdot2(w.y, h.y, acc[r]);
                        acc[r] = fdot2(w.z, h.z, acc[r]);
                        acc[r] = fdot2(w.w, h.w, acc[r]);
                    }
                }
            }
            #pragma unroll
            for (int r = 0; r < 8; ++r) red[(rq * 8 + r) * 256 + c] = acc[r];
            __syncthreads();
            if (rq == 0) {
                // p = red0+red1 -> online-softmax partial over 8 rows
                float pr8[8];
                #pragma unroll
                for (int r = 0; r < 8; ++r)
                    pr8[r] = red[r * 256 + c] + red[(8 + r) * 256 + c];
                float m8 = pr8[0];
                #pragma unroll
                for (int r = 1; r < 8; ++r) m8 = fmaxf(m8, pr8[r]);
                float d8 = 0.f, n8 = 0.f;
                #pragma unroll
                for (int r = 0; r < 8; ++r) {
                    const float e = __expf(pr8[r] - m8);
                    d8 += e;
                    n8 += e * xl32[r * 256 + c];
                }
                float* pb = part + (size_t)((i & 1) * 256 + bid) * 768;
                AG_ST(pb + c, m8);
                AG_ST(pb + 256 + c, d8);
                AG_ST(pb + 512 + c, n8);
            } else if (rq == 2) {
                #pragma unroll
                for (int r = 0; r < 8; ++r)
                    xu32[r * 256 + c] = red[(16 + r) * 256 + c] + red[(24 + r) * 256 + c];
            }
        }

        // ---- prefetch upcoming weight streams during the barrier window:
        // U2[i] (for phaseB(i)) and, if a next step exists, its P1/P2 mats.
        {
            unsigned pf = 0u;
            #pragma unroll
            for (int j = 0; j < 8; ++j) pf ^= wld(WtH, 9 + i, rq * 8 + j, c).x;
            if (i < 2) {
                #pragma unroll
                for (int j = 0; j < 8; ++j) pf ^= wld(WtH, i + 1, rq * 8 + j, c).x;
                const int mN = (rq < 2 ? 3 : 6) + i + 1;
                const int g0n = (rq & 1) * 16;
                #pragma unroll
                for (int j = 0; j < 16; ++j) pf ^= wld(WtH, mN, g0n + j, c).x;
            }
            if (tid == 0)   // consume pf: harmless store to unused flag word
                AG_ST(&flags[bid * FPAD + 8], pf);
        }
        gridbar(i + 2, flags, rel, bid, false);   // no fence: L2 stays warm
    }

    // ---- final combine + epilogue: out = xU1 + accU
    phaseB4(2, b, c, rq, tid, part, WtH, updB, red, aggl32, accu32, aggh);
    #pragma unroll
    for (int it = 0; it < 2; ++it) {
        const int idx = it * 1024 + tid;
        const int r = idx >> 8, cc = idx & 255;
        out[(size_t)(row0 + r) * 256 + cc] = xu32[r * 256 + cc] + accu32[cc];
    }
}

extern "C" void kernel_launch(void* const* d_in, const int* in_sizes, int n_in,
                              void* d_out, int out_size, void* d_ws, size_t ws_size,
                              hipStream_t stream) {
    const float* feat  = (const float*)d_in[0];
    const float* mask  = (const float*)d_in[1];
    const float* aggW  = (const float*)d_in[2];
    const float* aggB  = (const float*)d_in[3];
    const float* attnW = (const float*)d_in[4];
    // d_in[5] = attnB: cancels in softmax (constant along the s axis)
    const float* updW  = (const float*)d_in[6];
    const float* updB  = (const float*)d_in[7];

    unsigned* WtH = (unsigned*)d_ws;                   // 12 * 32768 uints
    float* part = (float*)(WtH + 12 * 32768);          // 2 * 256 * 768 floats
    unsigned* flags = (unsigned*)(part + 2 * 256 * 768);
    unsigned* rel   = flags + NBLK * FPAD;             // barriers * 16 lines

    fused_k<<<NBLK, 1024, 0, stream>>>(
        feat, mask, aggW, aggB, attnW, updW, updB,
        WtH, part, flags, rel, (float*)d_out);
}